// Round 6
// baseline (736.551 us; speedup 1.0000x reference)
//
#include <hip/hip_runtime.h>
#include <hip/hip_bf16.h>

// Problem constants (fixed by reference setup_inputs)
constexpr int Bn = 128;   // batch
constexpr int Tn = 32;    // timesteps
constexpr int Dn = 6400;  // input dim (K)
constexpr int Hn = 1000;  // hidden  (N)
constexpr int An = 4;     // actions
constexpr int Mn = Bn * Tn;   // 4096 GEMM rows
constexpr int Npad = 1024;    // W rows padded -> no N-guards in GEMM

constexpr int KS = Dn / 32;   // 200 k-chunks of 32

typedef _Float16 half8 __attribute__((ext_vector_type(8)));
typedef float floatx4 __attribute__((ext_vector_type(4)));

// Workspace layout (bytes). Paired split arrays: element (row, ks) is a 128-B
// group = [hi half8 x4 kg | lo half8 x4 kg] covering k = ks*32 .. +32.
constexpr size_t H1_BYTES  = (size_t)Mn * Hn * 4;        // 16,384,000
constexpr size_t XP_BYTES  = (size_t)Mn * Dn * 4;        // 104,857,600
constexpr size_t WP_BYTES  = (size_t)Npad * Dn * 4;      //  26,214,400
constexpr size_t WS_NEEDED = H1_BYTES + XP_BYTES + WP_BYTES;   // 147,456,000

// ---------------------------------------------------------------------------
// Pre-pass: fp16 hi/lo split (absmax 0.0 verified r2-r5), PAIRED layout.
// Thread i handles one 32-float group: reads 128 B contiguous, writes 128 B
// contiguous (wave: 8 KB runs both sides -- fully coalesced; r5's cvt gather
// was the hidden ~130 us). W rows >= Hn zeroed (group index >= Hn*KS).
// ---------------------------------------------------------------------------
__global__ __launch_bounds__(256)
void cvt_pair(const float* __restrict__ X, const float* __restrict__ W1,
              _Float16* __restrict__ Xp, _Float16* __restrict__ Wp)
{
    constexpr size_t nXg = (size_t)Mn * Dn / 32;    // 819,200 groups
    constexpr size_t nWg = (size_t)Npad * Dn / 32;  // 204,800 groups
    constexpr size_t nWreal = (size_t)Hn * KS;      // 200,000 real W groups
    const size_t i = (size_t)blockIdx.x * 256 + threadIdx.x;

    float v[32];
    _Float16* dst;
    if (i < nXg) {
        const float* src = X + i * 32;
#pragma unroll
        for (int j = 0; j < 8; ++j) *(float4*)&v[j * 4] = *(const float4*)(src + j * 4);
        dst = Xp + i * 64;
    } else if (i < nXg + nWg) {
        const size_t j = i - nXg;
        if (j < nWreal) {
            const float* src = W1 + j * 32;
#pragma unroll
            for (int q = 0; q < 8; ++q) *(float4*)&v[q * 4] = *(const float4*)(src + q * 4);
        } else {
#pragma unroll
            for (int q = 0; q < 32; ++q) v[q] = 0.f;
        }
        dst = Wp + j * 64;
    } else {
        return;
    }

    half8 hi[4], lo[4];
#pragma unroll
    for (int g = 0; g < 4; ++g)
#pragma unroll
        for (int j = 0; j < 8; ++j) {
            const float f = v[g * 8 + j];
            hi[g][j] = (_Float16)f;
            lo[g][j] = (_Float16)((f - (float)hi[g][j]) * 4096.0f);
        }
#pragma unroll
    for (int g = 0; g < 4; ++g) *(half8*)(dst + g * 8) = hi[g];
#pragma unroll
    for (int g = 0; g < 4; ++g) *(half8*)(dst + 32 + g * 8) = lo[g];
}

// ---------------------------------------------------------------------------
// GEMM: H1 = X @ W1^T + b1, fp16-split MFMA, ZERO LDS / ZERO barriers.
// Each wave loads its MFMA fragments directly global->VGPR (paired layout:
// lane l reads 16 B at (row = base + (l&15)) group offset (l>>4)*16 B; hi at
// +0, lo at +64 B). Wave-tile 64x32 (4x2 16x16x32 tiles, 24 MFMA / 12 loads
// per k-chunk), block tile 128x64 (2x2 waves -- L1 absorbs the x2 fragment
// redundancy), grid 32x16 = 512 blocks = 8 waves/CU (2/SIMD). Ping-pong
// register prefetch: loads for chunk k+1 issue before MFMAs of chunk k;
// only vmcnt waits, never a barrier drain (the r5 killer).
// ---------------------------------------------------------------------------
__global__ __launch_bounds__(256, 2)
void gemm_direct(const _Float16* __restrict__ Xp, const _Float16* __restrict__ Wp,
                 const float* __restrict__ b1, float* __restrict__ H1)
{
    const int tid = threadIdx.x;
    const int lane = tid & 63;
    const int w = tid >> 6;
    const int nb = blockIdx.x & 15;       // 16 n-blocks of 64  (XCD = bid%8 keeps W-slabs L2-local)
    const int mb = blockIdx.x >> 4;       // 32 m-blocks of 128
    const int wm = (w & 1) * 64;
    const int wn = (w >> 1) * 32;
    const int fr = lane & 15;
    const int kg = lane >> 4;             // 0..3

    // per-lane stream bases (halves); row stream advances 64 halves per ks
    const _Float16* abase[4];
    const _Float16* bbase[2];
#pragma unroll
    for (int mt = 0; mt < 4; ++mt)
        abase[mt] = Xp + (size_t)(mb * 128 + wm + mt * 16 + fr) * (KS * 64) + kg * 8;
#pragma unroll
    for (int nt = 0; nt < 2; ++nt)
        bbase[nt] = Wp + (size_t)(nb * 64 + wn + nt * 16 + fr) * (KS * 64) + kg * 8;

    half8 fa[2][4][2], fb[2][2][2];       // [buf][tile][hi/lo]
    floatx4 acc0[4][2] = {};
    floatx4 acc1[4][2] = {};

#define LOADF(ks, p)                                                          \
    {                                                                         \
        const size_t o = (size_t)(ks) * 64;                                   \
        _Pragma("unroll") for (int mt = 0; mt < 4; ++mt) {                    \
            fa[p][mt][0] = *(const half8*)(abase[mt] + o);                    \
            fa[p][mt][1] = *(const half8*)(abase[mt] + o + 32);               \
        }                                                                     \
        _Pragma("unroll") for (int nt = 0; nt < 2; ++nt) {                    \
            fb[p][nt][0] = *(const half8*)(bbase[nt] + o);                    \
            fb[p][nt][1] = *(const half8*)(bbase[nt] + o + 32);               \
        }                                                                     \
    }

#define COMPUTE(p)                                                            \
    _Pragma("unroll") for (int mt = 0; mt < 4; ++mt)                          \
        _Pragma("unroll") for (int nt = 0; nt < 2; ++nt) {                    \
            acc0[mt][nt] = __builtin_amdgcn_mfma_f32_16x16x32_f16(            \
                fa[p][mt][0], fb[p][nt][0], acc0[mt][nt], 0, 0, 0);           \
            acc1[mt][nt] = __builtin_amdgcn_mfma_f32_16x16x32_f16(            \
                fa[p][mt][0], fb[p][nt][1], acc1[mt][nt], 0, 0, 0);           \
            acc1[mt][nt] = __builtin_amdgcn_mfma_f32_16x16x32_f16(            \
                fa[p][mt][1], fb[p][nt][0], acc1[mt][nt], 0, 0, 0);           \
        }

    LOADF(0, 0)
#pragma unroll 1
    for (int it = 0; it < KS - 2; it += 2) {
        LOADF(it + 1, 1)
        COMPUTE(0)
        LOADF(it + 2, 0)
        COMPUTE(1)
    }
    LOADF(KS - 1, 1)
    COMPUTE(0)
    COMPUTE(1)
#undef LOADF
#undef COMPUTE

    // epilogue: C/D layout col=lane&15, row=(lane>>4)*4+r (verified r2-r5)
#pragma unroll
    for (int nt = 0; nt < 2; ++nt) {
        const int n = nb * 64 + wn + nt * 16 + fr;
        if (n >= Hn) continue;
        const float bias = b1[n];
#pragma unroll
        for (int mt = 0; mt < 4; ++mt) {
            const int m = mb * 128 + wm + mt * 16 + kg * 4;
#pragma unroll
            for (int r = 0; r < 4; ++r)
                H1[(size_t)(m + r) * Hn + n] =
                    acc0[mt][nt][r] + acc1[mt][nt][r] * (1.0f / 4096.0f) + bias;
        }
    }
}

// ---------------------------------------------------------------------------
// GEMM fallback (round-3 verified): only if ws_size < WS_NEEDED.
// ---------------------------------------------------------------------------
__global__ __launch_bounds__(256, 4)
void gemm_fb(const float* __restrict__ X, const float* __restrict__ W1,
             const float* __restrict__ b1, float* __restrict__ H1)
{
    constexpr int K = Dn;
    constexpr int LD = 72;
    __shared__ __align__(16) _Float16 As[2][64][LD];
    __shared__ __align__(16) _Float16 Bs[2][64][LD];

    const int tid = threadIdx.x;
    const int bm = blockIdx.x * 64;
    const int bn = blockIdx.y * 64;
    const int lane = tid & 63;
    const int wid = tid >> 6;
    const int wm = (wid & 1) * 32;
    const int wn = (wid >> 1) * 32;
    const int fr = lane & 15;
    const int fq = lane >> 4;

    const int row0 = tid >> 3;
    const int row1 = (tid + 256) >> 3;
    const int k8_0 = (tid & 7) * 8;

    float4 rx[2][2], rw[2][2];
    const float zero4[4] = {0.f, 0.f, 0.f, 0.f};

    auto load_tiles = [&](int k0) {
        rx[0][0] = *(const float4*)(X + (size_t)(bm + row0) * K + k0 + k8_0);
        rx[0][1] = *(const float4*)(X + (size_t)(bm + row0) * K + k0 + k8_0 + 4);
        rx[1][0] = *(const float4*)(X + (size_t)(bm + row1) * K + k0 + k8_0);
        rx[1][1] = *(const float4*)(X + (size_t)(bm + row1) * K + k0 + k8_0 + 4);
        const int n0 = bn + row0, n1 = bn + row1;
        if (n0 < Hn) {
            rw[0][0] = *(const float4*)(W1 + (size_t)n0 * K + k0 + k8_0);
            rw[0][1] = *(const float4*)(W1 + (size_t)n0 * K + k0 + k8_0 + 4);
        } else { rw[0][0] = *(const float4*)zero4; rw[0][1] = *(const float4*)zero4; }
        if (n1 < Hn) {
            rw[1][0] = *(const float4*)(W1 + (size_t)n1 * K + k0 + k8_0);
            rw[1][1] = *(const float4*)(W1 + (size_t)n1 * K + k0 + k8_0 + 4);
        } else { rw[1][0] = *(const float4*)zero4; rw[1][1] = *(const float4*)zero4; }
    };

    load_tiles(0);
    floatx4 acc0[2][2] = {};
    floatx4 acc1[2][2] = {};

    for (int k0 = 0; k0 < K; k0 += 64) {
#pragma unroll
        for (int p = 0; p < 2; ++p) {
            const int row = p ? row1 : row0;
            float v[8];
            *(float4*)&v[0] = rx[p][0]; *(float4*)&v[4] = rx[p][1];
            half8 hi, lo;
#pragma unroll
            for (int j = 0; j < 8; ++j) {
                hi[j] = (_Float16)v[j];
                lo[j] = (_Float16)((v[j] - (float)hi[j]) * 4096.0f);
            }
            *(half8*)&As[0][row][k8_0] = hi;
            *(half8*)&As[1][row][k8_0] = lo;

            *(float4*)&v[0] = rw[p][0]; *(float4*)&v[4] = rw[p][1];
#pragma unroll
            for (int j = 0; j < 8; ++j) {
                hi[j] = (_Float16)v[j];
                lo[j] = (_Float16)((v[j] - (float)hi[j]) * 4096.0f);
            }
            *(half8*)&Bs[0][row][k8_0] = hi;
            *(half8*)&Bs[1][row][k8_0] = lo;
        }
        __syncthreads();
        if (k0 + 64 < K) load_tiles(k0 + 64);

#pragma unroll
        for (int c = 0; c < 2; ++c) {
            half8 ahi[2], alo[2], bhi[2], blo[2];
#pragma unroll
            for (int mt = 0; mt < 2; ++mt) {
                ahi[mt] = *(const half8*)&As[0][wm + mt * 16 + fr][c * 32 + fq * 8];
                alo[mt] = *(const half8*)&As[1][wm + mt * 16 + fr][c * 32 + fq * 8];
            }
#pragma unroll
            for (int nt = 0; nt < 2; ++nt) {
                bhi[nt] = *(const half8*)&Bs[0][wn + nt * 16 + fr][c * 32 + fq * 8];
                blo[nt] = *(const half8*)&Bs[1][wn + nt * 16 + fr][c * 32 + fq * 8];
            }
#pragma unroll
            for (int mt = 0; mt < 2; ++mt)
#pragma unroll
                for (int nt = 0; nt < 2; ++nt) {
                    acc0[mt][nt] = __builtin_amdgcn_mfma_f32_16x16x32_f16(ahi[mt], bhi[nt], acc0[mt][nt], 0, 0, 0);
                    acc1[mt][nt] = __builtin_amdgcn_mfma_f32_16x16x32_f16(ahi[mt], blo[nt], acc1[mt][nt], 0, 0, 0);
                    acc1[mt][nt] = __builtin_amdgcn_mfma_f32_16x16x32_f16(alo[mt], bhi[nt], acc1[mt][nt], 0, 0, 0);
                }
        }
        __syncthreads();
    }

#pragma unroll
    for (int nt = 0; nt < 2; ++nt) {
        const int n = bn + wn + nt * 16 + fr;
        if (n >= Hn) continue;
        const float bias = b1[n];
#pragma unroll
        for (int mt = 0; mt < 2; ++mt) {
            const int m = bm + wm + mt * 16 + fq * 4;
#pragma unroll
            for (int r = 0; r < 4; ++r)
                H1[(size_t)(m + r) * Hn + n] =
                    acc0[mt][nt][r] + acc1[mt][nt][r] * (1.0f / 4096.0f) + bias;
        }
    }
}

// ---------------------------------------------------------------------------
// LIF scan, barrier-light (r4/r5 version, verified).
// ---------------------------------------------------------------------------
__global__ __launch_bounds__(1024)
void snn_scan(const float* __restrict__ H1, const float* __restrict__ W2,
              const float* __restrict__ b2, float* __restrict__ out)
{
    const int b = blockIdx.x;
    const int tid = threadIdx.x;
    const int lane = tid & 63;
    const int wid = tid >> 6;
    const bool act = (tid < Hn);

    __shared__ float w2s[1024][5];
    __shared__ unsigned smask[1024];
    __shared__ float h2s[Tn][An];

#pragma unroll
    for (int a = 0; a < An; ++a)
        w2s[tid][a] = act ? W2[a * Hn + tid] : 0.f;

    float cur[Tn];
#pragma unroll
    for (int t = 0; t < Tn; ++t)
        cur[t] = act ? H1[((size_t)b * Tn + t) * Hn + tid] : 0.f;

    unsigned mask = 0;
    float mem1 = 0.f;
#pragma unroll
    for (int t = 0; t < Tn; ++t) {
        const float reset = (mem1 > 1.0f) ? 1.0f : 0.0f;
        mem1 = (0.99f * mem1 + cur[t]) * (1.0f - reset);
        if (mem1 > 1.0f) mask |= (1u << t);
    }
    smask[tid] = mask;
    __syncthreads();

#pragma unroll
    for (int tt = 0; tt < 2; ++tt) {
        const int t = wid * 2 + tt;
        float p[An] = {0.f, 0.f, 0.f, 0.f};
        for (int h = lane; h < 1024; h += 64) {
            const float g = (smask[h] >> t) & 1u ? 1.0f : 0.0f;
#pragma unroll
            for (int a = 0; a < An; ++a) p[a] += g * w2s[h][a];
        }
#pragma unroll
        for (int off = 32; off > 0; off >>= 1)
#pragma unroll
            for (int a = 0; a < An; ++a) p[a] += __shfl_down(p[a], off, 64);
        if (lane == 0) {
#pragma unroll
            for (int a = 0; a < An; ++a) h2s[t][a] = p[a];
        }
    }
    __syncthreads();

    if (tid < An) {
        const float bias = b2[tid];
        float mem2 = 0.f;
#pragma unroll
        for (int t = 0; t < Tn; ++t) {
            const float h2 = h2s[t][tid] + bias;
            const float reset = (mem2 > 1.0f) ? 1.0f : 0.0f;
            mem2 = (0.99f * mem2 + h2) * (1.0f - reset);
            out[((size_t)b * Tn + t) * An + tid] = (mem2 > 1.0f) ? 1.0f : 0.0f;
        }
    }
}

extern "C" void kernel_launch(void* const* d_in, const int* in_sizes, int n_in,
                              void* d_out, int out_size, void* d_ws, size_t ws_size,
                              hipStream_t stream) {
    const float* x  = (const float*)d_in[0];   // [B,T,D]
    const float* W1 = (const float*)d_in[1];   // [H,D]
    const float* b1 = (const float*)d_in[2];   // [H]
    const float* W2 = (const float*)d_in[3];   // [A,H]
    const float* b2 = (const float*)d_in[4];   // [A]
    float* out = (float*)d_out;                // [B,T,A]

    char* ws = (char*)d_ws;
    float* H1 = (float*)ws;

    if (ws_size >= WS_NEEDED) {
        _Float16* Xp = (_Float16*)(ws + H1_BYTES);
        _Float16* Wp = (_Float16*)(ws + H1_BYTES + XP_BYTES);

        constexpr size_t ng = ((size_t)Mn * Dn + (size_t)Npad * Dn) / 32;  // 1,024,000
        cvt_pair<<<(unsigned)((ng + 255) / 256), 256, 0, stream>>>(x, W1, Xp, Wp);

        gemm_direct<<<512, 256, 0, stream>>>(Xp, Wp, b1, H1);   // bid: n=&15, m=>>4
    } else {
        dim3 grid(Mn / 64, (Hn + 63) / 64);
        gemm_fb<<<grid, 256, 0, stream>>>(x, W1, b1, H1);
    }
    snn_scan<<<Bn, 1024, 0, stream>>>(H1, W2, b2, out);
}

// Round 7
// 366.712 us; speedup vs baseline: 2.0085x; 2.0085x over previous
//
#include <hip/hip_runtime.h>
#include <hip/hip_bf16.h>

// Problem constants (fixed by reference setup_inputs)
constexpr int Bn = 128;   // batch
constexpr int Tn = 32;    // timesteps
constexpr int Dn = 6400;  // input dim (K)
constexpr int Hn = 1000;  // hidden  (N)
constexpr int An = 4;     // actions
constexpr int Mn = Bn * Tn;   // 4096 GEMM rows
constexpr int Npad = 1024;    // W rows padded -> no N-guards in GEMM

constexpr int KS = Dn / 32;   // 200 k-chunks of 32
constexpr int MC = Mn / 16;   // 256 m-chunks of 16 rows
constexpr int NC = Npad / 16; // 64  n-chunks of 16 rows

typedef _Float16 half8 __attribute__((ext_vector_type(8)));
typedef _Float16 half4 __attribute__((ext_vector_type(4)));
typedef float floatx4 __attribute__((ext_vector_type(4)));

// Workspace layout (bytes) -- identical to r5 (granted by harness).
constexpr size_t H1_BYTES  = (size_t)Mn * Hn * 4;
constexpr size_t XS_BYTES  = (size_t)Mn * Dn * 2;       // per split
constexpr size_t WSp_BYTES = (size_t)Npad * Dn * 2;     // per split
constexpr size_t WS_NEEDED = H1_BYTES + 2 * XS_BYTES + 2 * WSp_BYTES;

__device__ __forceinline__ void async16(const void* g, void* l) {
    __builtin_amdgcn_global_load_lds(
        (const __attribute__((address_space(1))) void*)g,
        (__attribute__((address_space(3))) void*)l, 16, 0, 0);
}

// ---------------------------------------------------------------------------
// Pre-pass: fp16 hi/lo split (absmax 0.0 r2-r6) into the fragment-chunk
// layout, with BOTH sides 1KB-per-instruction coalesced via an LDS transpose.
// (r5's cvt read-gathered 16-row scatter; r6's cvt had per-thread-contiguous
// = per-instruction-strided access. Coalescing is per-instruction across
// lanes -- this kernel finally respects that.)
// Block handles 16 rows x 256 k (8 ks-chunks): read phase wave w reads rows
// 4w..4w+3, lane l one float4 at col l*4 (1 KB contiguous/instr); write phase
// wave w emits ks=2w,2w+1 chunks: lane l writes half8 at chunk_base + l*16 B
// (1 KB contiguous/instr). LDS row pad 264 halves -> write-phase reads are
// bank-uniform.
// ---------------------------------------------------------------------------
__global__ __launch_bounds__(256)
void cvt2(const float* __restrict__ X, const float* __restrict__ W1,
          _Float16* __restrict__ Xh, _Float16* __restrict__ Xl,
          _Float16* __restrict__ Wh, _Float16* __restrict__ Wl)
{
    constexpr int LD2 = 264;
    __shared__ __align__(16) _Float16 hiS[16][LD2];
    __shared__ __align__(16) _Float16 loS[16][LD2];

    const int tid = threadIdx.x;
    const int lane = tid & 63;
    const int w = tid >> 6;
    const int bx = blockIdx.x;

    const float* src;
    _Float16 *dh, *dl;
    int c4, ks0, crow, nrows;
    if (bx < 256 * 25) {                       // X part
        c4 = bx & 255; ks0 = (bx >> 8) * 8;
        src = X; dh = Xh; dl = Xl; crow = MC; nrows = 16;
    } else {                                   // W part (rows >= Hn zeroed)
        const int b2 = bx - 256 * 25;
        c4 = b2 & 63; ks0 = (b2 >> 6) * 8;
        src = W1; dh = Wh; dl = Wl; crow = NC; nrows = Hn - c4 * 16;
    }

    // read + convert (wave w: rows 4w..4w+3)
#pragma unroll
    for (int j = 0; j < 4; ++j) {
        const int row = w * 4 + j;
        float4 v = make_float4(0.f, 0.f, 0.f, 0.f);
        if (row < nrows)
            v = *(const float4*)(src + (size_t)(c4 * 16 + row) * Dn + ks0 * 32 + lane * 4);
        half4 hi, lo;
        hi[0] = (_Float16)v.x; lo[0] = (_Float16)((v.x - (float)hi[0]) * 4096.0f);
        hi[1] = (_Float16)v.y; lo[1] = (_Float16)((v.y - (float)hi[1]) * 4096.0f);
        hi[2] = (_Float16)v.z; lo[2] = (_Float16)((v.z - (float)hi[2]) * 4096.0f);
        hi[3] = (_Float16)v.w; lo[3] = (_Float16)((v.w - (float)hi[3]) * 4096.0f);
        *(half4*)&hiS[row][lane * 4] = hi;
        *(half4*)&loS[row][lane * 4] = lo;
    }
    __syncthreads();

    // write chunks (wave w: ks = 2w, 2w+1)
    const int lr = lane & 15, lg = lane >> 4;
#pragma unroll
    for (int q = 0; q < 2; ++q) {
        const int ks = w * 2 + q;
        const size_t cbase = ((size_t)(ks0 + ks) * crow + c4) * 512;
        const half8 h = *(const half8*)&hiS[lr][ks * 32 + lg * 8];
        const half8 l = *(const half8*)&loS[lr][ks * 32 + lg * 8];
        *(half8*)(dh + cbase + lane * 8) = h;
        *(half8*)(dl + cbase + lane * 8) = l;
    }
}

// ---------------------------------------------------------------------------
// GEMM: H1 = X @ W1^T + b1, fp16-split MFMA on fragment-chunked inputs.
// r5 structure (chunked LDS + global_load_lds 16B + zero conflicts) but
// block tile 128x64 -> grid 512 = 2 blocks/CU co-resident: the per-iter
// barrier drain of one block overlaps the other block's MFMAs (the r5
// killer was grid 256 = 1 block/CU, nothing to overlap). Double-buffered
// 2x24 KB LDS; waves 2x2, wave-tile 64x32 (4x2 16x16x32 tiles, 24 MFMA /
// 12 KB LDS reads per iter). Floors: MFMA ~78 us (161 GF @ 2.0 PF measured),
// LDS ~107 us -> expect ~130 us.
// ---------------------------------------------------------------------------
constexpr int AH = 0;           // halves offsets inside one LDS buffer
constexpr int AL = 8 * 512;
constexpr int BH = 16 * 512;
constexpr int BL = 20 * 512;
constexpr int BUFSZ = 24 * 512; // 24 KB per buffer

__global__ __launch_bounds__(256, 2)
void gemm_frag2(const _Float16* __restrict__ Xh, const _Float16* __restrict__ Xl,
                const _Float16* __restrict__ Wh, const _Float16* __restrict__ Wl,
                const float* __restrict__ b1, float* __restrict__ H1)
{
    __shared__ __align__(16) _Float16 S[2 * BUFSZ];

    const int tid = threadIdx.x;
    const int lane = tid & 63;
    const int w = tid >> 6;
    const int nb = blockIdx.x & 15;   // 16 n-blocks of 64
    const int mb = blockIdx.x >> 4;   // 32 m-blocks of 128
    const int bm4 = mb * 8;
    const int bn4 = nb * 4;
    const int wm = w & 1;
    const int wn = w >> 1;

    auto issue = [&](int ks, int buf) {
        _Float16* base = &S[buf * BUFSZ];
#pragma unroll
        for (int r = 0; r < 2; ++r) {
            const int i = w * 2 + r;                       // A chunks 2w, 2w+1
            const size_t ga = ((size_t)(ks * MC + bm4 + i)) * 512 + lane * 8;
            async16(Xh + ga, base + AH + i * 512);
            async16(Xl + ga, base + AL + i * 512);
        }
        const size_t gb = ((size_t)(ks * NC + bn4 + w)) * 512 + lane * 8;  // B chunk w
        async16(Wh + gb, base + BH + w * 512);
        async16(Wl + gb, base + BL + w * 512);
    };

    floatx4 acc0[4][2] = {};
    floatx4 acc1[4][2] = {};

    issue(0, 0);
    for (int it = 0; it < KS; ++it) {
        const int buf = it & 1;
        __syncthreads();                   // drains DMA for buf; frees buf^1
        if (it + 1 < KS) issue(it + 1, buf ^ 1);

        const _Float16* base = &S[buf * BUFSZ];
        half8 ah[4], al[4], bh[2], bl[2];
#pragma unroll
        for (int mt = 0; mt < 4; ++mt) {
            ah[mt] = *(const half8*)(base + AH + (wm * 4 + mt) * 512 + lane * 8);
            al[mt] = *(const half8*)(base + AL + (wm * 4 + mt) * 512 + lane * 8);
        }
#pragma unroll
        for (int nt = 0; nt < 2; ++nt) {
            bh[nt] = *(const half8*)(base + BH + (wn * 2 + nt) * 512 + lane * 8);
            bl[nt] = *(const half8*)(base + BL + (wn * 2 + nt) * 512 + lane * 8);
        }
#pragma unroll
        for (int mt = 0; mt < 4; ++mt)
#pragma unroll
            for (int nt = 0; nt < 2; ++nt) {
                acc0[mt][nt] = __builtin_amdgcn_mfma_f32_16x16x32_f16(ah[mt], bh[nt], acc0[mt][nt], 0, 0, 0);
                acc1[mt][nt] = __builtin_amdgcn_mfma_f32_16x16x32_f16(ah[mt], bl[nt], acc1[mt][nt], 0, 0, 0);
                acc1[mt][nt] = __builtin_amdgcn_mfma_f32_16x16x32_f16(al[mt], bh[nt], acc1[mt][nt], 0, 0, 0);
            }
    }

    // epilogue: C/D layout col=lane&15, row=(lane>>4)*4+r (verified r2-r6)
    const int fr = lane & 15;
    const int fq = lane >> 4;
#pragma unroll
    for (int nt = 0; nt < 2; ++nt) {
        const int n = nb * 64 + wn * 32 + nt * 16 + fr;
        if (n >= Hn) continue;
        const float bias = b1[n];
#pragma unroll
        for (int mt = 0; mt < 4; ++mt) {
            const int m = mb * 128 + wm * 64 + mt * 16 + fq * 4;
#pragma unroll
            for (int r = 0; r < 4; ++r)
                H1[(size_t)(m + r) * Hn + n] =
                    acc0[mt][nt][r] + acc1[mt][nt][r] * (1.0f / 4096.0f) + bias;
        }
    }
}

// ---------------------------------------------------------------------------
// GEMM fallback (round-3 verified): only if ws_size < WS_NEEDED.
// ---------------------------------------------------------------------------
__global__ __launch_bounds__(256, 4)
void gemm_fb(const float* __restrict__ X, const float* __restrict__ W1,
             const float* __restrict__ b1, float* __restrict__ H1)
{
    constexpr int K = Dn;
    constexpr int LD = 72;
    __shared__ __align__(16) _Float16 As[2][64][LD];
    __shared__ __align__(16) _Float16 Bs[2][64][LD];

    const int tid = threadIdx.x;
    const int bm = blockIdx.x * 64;
    const int bn = blockIdx.y * 64;
    const int lane = tid & 63;
    const int wid = tid >> 6;
    const int wm = (wid & 1) * 32;
    const int wn = (wid >> 1) * 32;
    const int fr = lane & 15;
    const int fq = lane >> 4;

    const int row0 = tid >> 3;
    const int row1 = (tid + 256) >> 3;
    const int k8_0 = (tid & 7) * 8;

    float4 rx[2][2], rw[2][2];
    const float zero4[4] = {0.f, 0.f, 0.f, 0.f};

    auto load_tiles = [&](int k0) {
        rx[0][0] = *(const float4*)(X + (size_t)(bm + row0) * K + k0 + k8_0);
        rx[0][1] = *(const float4*)(X + (size_t)(bm + row0) * K + k0 + k8_0 + 4);
        rx[1][0] = *(const float4*)(X + (size_t)(bm + row1) * K + k0 + k8_0);
        rx[1][1] = *(const float4*)(X + (size_t)(bm + row1) * K + k0 + k8_0 + 4);
        const int n0 = bn + row0, n1 = bn + row1;
        if (n0 < Hn) {
            rw[0][0] = *(const float4*)(W1 + (size_t)n0 * K + k0 + k8_0);
            rw[0][1] = *(const float4*)(W1 + (size_t)n0 * K + k0 + k8_0 + 4);
        } else { rw[0][0] = *(const float4*)zero4; rw[0][1] = *(const float4*)zero4; }
        if (n1 < Hn) {
            rw[1][0] = *(const float4*)(W1 + (size_t)n1 * K + k0 + k8_0);
            rw[1][1] = *(const float4*)(W1 + (size_t)n1 * K + k0 + k8_0 + 4);
        } else { rw[1][0] = *(const float4*)zero4; rw[1][1] = *(const float4*)zero4; }
    };

    load_tiles(0);
    floatx4 acc0[2][2] = {};
    floatx4 acc1[2][2] = {};

    for (int k0 = 0; k0 < K; k0 += 64) {
#pragma unroll
        for (int p = 0; p < 2; ++p) {
            const int row = p ? row1 : row0;
            float v[8];
            *(float4*)&v[0] = rx[p][0]; *(float4*)&v[4] = rx[p][1];
            half8 hi, lo;
#pragma unroll
            for (int j = 0; j < 8; ++j) {
                hi[j] = (_Float16)v[j];
                lo[j] = (_Float16)((v[j] - (float)hi[j]) * 4096.0f);
            }
            *(half8*)&As[0][row][k8_0] = hi;
            *(half8*)&As[1][row][k8_0] = lo;

            *(float4*)&v[0] = rw[p][0]; *(float4*)&v[4] = rw[p][1];
#pragma unroll
            for (int j = 0; j < 8; ++j) {
                hi[j] = (_Float16)v[j];
                lo[j] = (_Float16)((v[j] - (float)hi[j]) * 4096.0f);
            }
            *(half8*)&Bs[0][row][k8_0] = hi;
            *(half8*)&Bs[1][row][k8_0] = lo;
        }
        __syncthreads();
        if (k0 + 64 < K) load_tiles(k0 + 64);

#pragma unroll
        for (int c = 0; c < 2; ++c) {
            half8 ahi[2], alo[2], bhi[2], blo[2];
#pragma unroll
            for (int mt = 0; mt < 2; ++mt) {
                ahi[mt] = *(const half8*)&As[0][wm + mt * 16 + fr][c * 32 + fq * 8];
                alo[mt] = *(const half8*)&As[1][wm + mt * 16 + fr][c * 32 + fq * 8];
            }
#pragma unroll
            for (int nt = 0; nt < 2; ++nt) {
                bhi[nt] = *(const half8*)&Bs[0][wn + nt * 16 + fr][c * 32 + fq * 8];
                blo[nt] = *(const half8*)&Bs[1][wn + nt * 16 + fr][c * 32 + fq * 8];
            }
#pragma unroll
            for (int mt = 0; mt < 2; ++mt)
#pragma unroll
                for (int nt = 0; nt < 2; ++nt) {
                    acc0[mt][nt] = __builtin_amdgcn_mfma_f32_16x16x32_f16(ahi[mt], bhi[nt], acc0[mt][nt], 0, 0, 0);
                    acc1[mt][nt] = __builtin_amdgcn_mfma_f32_16x16x32_f16(ahi[mt], blo[nt], acc1[mt][nt], 0, 0, 0);
                    acc1[mt][nt] = __builtin_amdgcn_mfma_f32_16x16x32_f16(alo[mt], bhi[nt], acc1[mt][nt], 0, 0, 0);
                }
        }
        __syncthreads();
    }

#pragma unroll
    for (int nt = 0; nt < 2; ++nt) {
        const int n = bn + wn + nt * 16 + fr;
        if (n >= Hn) continue;
        const float bias = b1[n];
#pragma unroll
        for (int mt = 0; mt < 2; ++mt) {
            const int m = bm + wm + mt * 16 + fq * 4;
#pragma unroll
            for (int r = 0; r < 4; ++r)
                H1[(size_t)(m + r) * Hn + n] =
                    acc0[mt][nt][r] + acc1[mt][nt][r] * (1.0f / 4096.0f) + bias;
        }
    }
}

// ---------------------------------------------------------------------------
// LIF scan, barrier-light (verified r4-r6).
// ---------------------------------------------------------------------------
__global__ __launch_bounds__(1024)
void snn_scan(const float* __restrict__ H1, const float* __restrict__ W2,
              const float* __restrict__ b2, float* __restrict__ out)
{
    const int b = blockIdx.x;
    const int tid = threadIdx.x;
    const int lane = tid & 63;
    const int wid = tid >> 6;
    const bool act = (tid < Hn);

    __shared__ float w2s[1024][5];
    __shared__ unsigned smask[1024];
    __shared__ float h2s[Tn][An];

#pragma unroll
    for (int a = 0; a < An; ++a)
        w2s[tid][a] = act ? W2[a * Hn + tid] : 0.f;

    float cur[Tn];
#pragma unroll
    for (int t = 0; t < Tn; ++t)
        cur[t] = act ? H1[((size_t)b * Tn + t) * Hn + tid] : 0.f;

    unsigned mask = 0;
    float mem1 = 0.f;
#pragma unroll
    for (int t = 0; t < Tn; ++t) {
        const float reset = (mem1 > 1.0f) ? 1.0f : 0.0f;
        mem1 = (0.99f * mem1 + cur[t]) * (1.0f - reset);
        if (mem1 > 1.0f) mask |= (1u << t);
    }
    smask[tid] = mask;
    __syncthreads();

#pragma unroll
    for (int tt = 0; tt < 2; ++tt) {
        const int t = wid * 2 + tt;
        float p[An] = {0.f, 0.f, 0.f, 0.f};
        for (int h = lane; h < 1024; h += 64) {
            const float g = (smask[h] >> t) & 1u ? 1.0f : 0.0f;
#pragma unroll
            for (int a = 0; a < An; ++a) p[a] += g * w2s[h][a];
        }
#pragma unroll
        for (int off = 32; off > 0; off >>= 1)
#pragma unroll
            for (int a = 0; a < An; ++a) p[a] += __shfl_down(p[a], off, 64);
        if (lane == 0) {
#pragma unroll
            for (int a = 0; a < An; ++a) h2s[t][a] = p[a];
        }
    }
    __syncthreads();

    if (tid < An) {
        const float bias = b2[tid];
        float mem2 = 0.f;
#pragma unroll
        for (int t = 0; t < Tn; ++t) {
            const float h2 = h2s[t][tid] + bias;
            const float reset = (mem2 > 1.0f) ? 1.0f : 0.0f;
            mem2 = (0.99f * mem2 + h2) * (1.0f - reset);
            out[((size_t)b * Tn + t) * An + tid] = (mem2 > 1.0f) ? 1.0f : 0.0f;
        }
    }
}

extern "C" void kernel_launch(void* const* d_in, const int* in_sizes, int n_in,
                              void* d_out, int out_size, void* d_ws, size_t ws_size,
                              hipStream_t stream) {
    const float* x  = (const float*)d_in[0];   // [B,T,D]
    const float* W1 = (const float*)d_in[1];   // [H,D]
    const float* b1 = (const float*)d_in[2];   // [H]
    const float* W2 = (const float*)d_in[3];   // [A,H]
    const float* b2 = (const float*)d_in[4];   // [A]
    float* out = (float*)d_out;                // [B,T,A]

    char* ws = (char*)d_ws;
    float* H1 = (float*)ws;

    if (ws_size >= WS_NEEDED) {
        _Float16* Xh = (_Float16*)(ws + H1_BYTES);
        _Float16* Xl = (_Float16*)(ws + H1_BYTES + XS_BYTES);
        _Float16* Wh = (_Float16*)(ws + H1_BYTES + 2 * XS_BYTES);
        _Float16* Wl = (_Float16*)(ws + H1_BYTES + 2 * XS_BYTES + WSp_BYTES);

        cvt2<<<256 * 25 + 64 * 25, 256, 0, stream>>>(x, W1, Xh, Xl, Wh, Wl);
        gemm_frag2<<<512, 256, 0, stream>>>(Xh, Xl, Wh, Wl, b1, H1);   // bid: n=&15, m=>>4
    } else {
        dim3 grid(Mn / 64, (Hn + 63) / 64);
        gemm_fb<<<grid, 256, 0, stream>>>(x, W1, b1, H1);
    }
    snn_scan<<<Bn, 1024, 0, stream>>>(H1, W2, b2, out);
}

// Round 8
// 349.531 us; speedup vs baseline: 2.1073x; 1.0492x over previous
//
#include <hip/hip_runtime.h>
#include <hip/hip_bf16.h>

// Problem constants (fixed by reference setup_inputs)
constexpr int Bn = 128;   // batch
constexpr int Tn = 32;    // timesteps
constexpr int Dn = 6400;  // input dim (K)
constexpr int Hn = 1000;  // hidden  (N)
constexpr int An = 4;     // actions
constexpr int Mn = Bn * Tn;   // 4096 GEMM rows
constexpr int Npad = 1024;    // W rows padded -> no N-guards in GEMM

constexpr int KS = Dn / 32;   // 200 k-chunks of 32
constexpr int MC = Mn / 16;   // 256 m-chunks of 16 rows
constexpr int NC = Npad / 16; // 64  n-chunks of 16 rows

typedef _Float16 half8 __attribute__((ext_vector_type(8)));
typedef _Float16 half4 __attribute__((ext_vector_type(4)));
typedef float floatx4 __attribute__((ext_vector_type(4)));

// Workspace layouts (bytes)
constexpr size_t H1_BYTES  = (size_t)Mn * Hn * 4;       // 16,384,000
constexpr size_t XS_BYTES  = (size_t)Mn * Dn * 2;       // per split
constexpr size_t WSp_BYTES = (size_t)Npad * Dn * 2;     // per split
constexpr size_t WS_R7     = H1_BYTES + 2 * XS_BYTES + 2 * WSp_BYTES;      // 147,456,000
constexpr size_t WS_SPLITK = 2 * H1_BYTES + 2 * XS_BYTES + 2 * WSp_BYTES;  // 163,840,000

__device__ __forceinline__ void async16(const void* g, void* l) {
    __builtin_amdgcn_global_load_lds(
        (const __attribute__((address_space(1))) void*)g,
        (__attribute__((address_space(3))) void*)l, 16, 0, 0);
}

// ---------------------------------------------------------------------------
// Pre-pass (r7-verified): fp16 hi/lo split into fragment-chunk layout, both
// sides 1KB-per-instruction coalesced via LDS transpose.
// ---------------------------------------------------------------------------
__global__ __launch_bounds__(256)
void cvt2(const float* __restrict__ X, const float* __restrict__ W1,
          _Float16* __restrict__ Xh, _Float16* __restrict__ Xl,
          _Float16* __restrict__ Wh, _Float16* __restrict__ Wl)
{
    constexpr int LD2 = 264;
    __shared__ __align__(16) _Float16 hiS[16][LD2];
    __shared__ __align__(16) _Float16 loS[16][LD2];

    const int tid = threadIdx.x;
    const int lane = tid & 63;
    const int w = tid >> 6;
    const int bx = blockIdx.x;

    const float* src;
    _Float16 *dh, *dl;
    int c4, ks0, crow, nrows;
    if (bx < 256 * 25) {                       // X part
        c4 = bx & 255; ks0 = (bx >> 8) * 8;
        src = X; dh = Xh; dl = Xl; crow = MC; nrows = 16;
    } else {                                   // W part (rows >= Hn zeroed)
        const int b2 = bx - 256 * 25;
        c4 = b2 & 63; ks0 = (b2 >> 6) * 8;
        src = W1; dh = Wh; dl = Wl; crow = NC; nrows = Hn - c4 * 16;
    }

#pragma unroll
    for (int j = 0; j < 4; ++j) {
        const int row = w * 4 + j;
        float4 v = make_float4(0.f, 0.f, 0.f, 0.f);
        if (row < nrows)
            v = *(const float4*)(src + (size_t)(c4 * 16 + row) * Dn + ks0 * 32 + lane * 4);
        half4 hi, lo;
        hi[0] = (_Float16)v.x; lo[0] = (_Float16)((v.x - (float)hi[0]) * 4096.0f);
        hi[1] = (_Float16)v.y; lo[1] = (_Float16)((v.y - (float)hi[1]) * 4096.0f);
        hi[2] = (_Float16)v.z; lo[2] = (_Float16)((v.z - (float)hi[2]) * 4096.0f);
        hi[3] = (_Float16)v.w; lo[3] = (_Float16)((v.w - (float)hi[3]) * 4096.0f);
        *(half4*)&hiS[row][lane * 4] = hi;
        *(half4*)&loS[row][lane * 4] = lo;
    }
    __syncthreads();

    const int lr = lane & 15, lg = lane >> 4;
#pragma unroll
    for (int q = 0; q < 2; ++q) {
        const int ks = w * 2 + q;
        const size_t cbase = ((size_t)(ks0 + ks) * crow + c4) * 512;
        const half8 h = *(const half8*)&hiS[lr][ks * 32 + lg * 8];
        const half8 l = *(const half8*)&loS[lr][ks * 32 + lg * 8];
        *(half8*)(dh + cbase + lane * 8) = h;
        *(half8*)(dl + cbase + lane * 8) = l;
    }
}

// ---------------------------------------------------------------------------
// GEMM (primary): 128x128 tile, split-K=2 -> grid 512 = 2 blocks/CU.
// r5's fetch-efficient big tile (raw demand 1.7 GB vs r7's 2.5 GB, 48 MFMA
// per 16 ds_read_b128 per wave-iter) + r7's co-residency (the r5 killer was
// grid 256 = 1 block/CU: barrier drains had nothing to overlap). Double-
// buffered 2x32 KB LDS, 100 iters per block. kh half writes partial (no
// bias) to H1 + kh*M*N; scan sums. bid: kh=&1, nb=(>>1)&7, mb=>>4 -> per-XCD
// W slab 2x1.64 MB (L2-resident).
// ---------------------------------------------------------------------------
__global__ __launch_bounds__(256, 2)
void gemm_sk(const _Float16* __restrict__ Xh, const _Float16* __restrict__ Xl,
             const _Float16* __restrict__ Wh, const _Float16* __restrict__ Wl,
             float* __restrict__ H1)
{
    __shared__ __align__(16) _Float16 S[2][32][512];   // 64 KB: [buf][chunk][1KB]

    const int tid = threadIdx.x;
    const int lane = tid & 63;
    const int w = tid >> 6;
    const int kh = blockIdx.x & 1;
    const int nb = (blockIdx.x >> 1) & 7;
    const int mb = blockIdx.x >> 4;
    const int bm8 = mb * 8;
    const int bn8 = nb * 8;
    const int wm = w & 1;
    const int wn = w >> 1;
    const int ks0 = kh * (KS / 2);

    auto issue = [&](int ks, int buf) {
        _Float16* base = &S[buf][0][0];
#pragma unroll
        for (int r = 0; r < 2; ++r) {
            const int i = w * 2 + r;
            const size_t ga = ((size_t)(ks * MC + bm8 + i)) * 512 + lane * 8;
            const size_t gb = ((size_t)(ks * NC + bn8 + i)) * 512 + lane * 8;
            async16(Xh + ga, base + (0 + i) * 512);
            async16(Xl + ga, base + (8 + i) * 512);
            async16(Wh + gb, base + (16 + i) * 512);
            async16(Wl + gb, base + (24 + i) * 512);
        }
    };

    floatx4 acc0[4][4] = {};
    floatx4 acc1[4][4] = {};

    issue(ks0, 0);
    for (int it = 0; it < KS / 2; ++it) {
        const int buf = it & 1;
        __syncthreads();                   // DMA for buf landed; buf^1 free
        if (it + 1 < KS / 2) issue(ks0 + it + 1, buf ^ 1);

        half8 ah[4], al[4], bh[4], bl[4];
#pragma unroll
        for (int mt = 0; mt < 4; ++mt) {
            ah[mt] = *(const half8*)&S[buf][wm * 4 + mt][lane * 8];
            al[mt] = *(const half8*)&S[buf][8 + wm * 4 + mt][lane * 8];
        }
#pragma unroll
        for (int nt = 0; nt < 4; ++nt) {
            bh[nt] = *(const half8*)&S[buf][16 + wn * 4 + nt][lane * 8];
            bl[nt] = *(const half8*)&S[buf][24 + wn * 4 + nt][lane * 8];
        }
#pragma unroll
        for (int mt = 0; mt < 4; ++mt)
#pragma unroll
            for (int nt = 0; nt < 4; ++nt) {
                acc0[mt][nt] = __builtin_amdgcn_mfma_f32_16x16x32_f16(ah[mt], bh[nt], acc0[mt][nt], 0, 0, 0);
                acc1[mt][nt] = __builtin_amdgcn_mfma_f32_16x16x32_f16(ah[mt], bl[nt], acc1[mt][nt], 0, 0, 0);
                acc1[mt][nt] = __builtin_amdgcn_mfma_f32_16x16x32_f16(al[mt], bh[nt], acc1[mt][nt], 0, 0, 0);
            }
    }

    // epilogue (no bias -- scan adds b1): C/D col=lane&15, row=(lane>>4)*4+r
    float* H1o = H1 + (size_t)kh * ((size_t)Mn * Hn);
    const int fr = lane & 15;
    const int fq = lane >> 4;
#pragma unroll
    for (int nt = 0; nt < 4; ++nt) {
        const int n = nb * 128 + wn * 64 + nt * 16 + fr;
        if (n >= Hn) continue;
#pragma unroll
        for (int mt = 0; mt < 4; ++mt) {
            const int m = mb * 128 + wm * 64 + mt * 16 + fq * 4;
#pragma unroll
            for (int r = 0; r < 4; ++r)
                H1o[(size_t)(m + r) * Hn + n] =
                    acc0[mt][nt][r] + acc1[mt][nt][r] * (1.0f / 4096.0f);
        }
    }
}

// ---------------------------------------------------------------------------
// GEMM mid-fallback (r7-verified, 163 us; bias removed): ws in [147,164) MB.
// ---------------------------------------------------------------------------
constexpr int AH = 0;
constexpr int AL = 8 * 512;
constexpr int BH = 16 * 512;
constexpr int BL = 20 * 512;
constexpr int BUFSZ = 24 * 512;

__global__ __launch_bounds__(256, 2)
void gemm_frag2(const _Float16* __restrict__ Xh, const _Float16* __restrict__ Xl,
                const _Float16* __restrict__ Wh, const _Float16* __restrict__ Wl,
                float* __restrict__ H1)
{
    __shared__ __align__(16) _Float16 S[2 * BUFSZ];

    const int tid = threadIdx.x;
    const int lane = tid & 63;
    const int w = tid >> 6;
    const int nb = blockIdx.x & 15;
    const int mb = blockIdx.x >> 4;
    const int bm4 = mb * 8;
    const int bn4 = nb * 4;
    const int wm = w & 1;
    const int wn = w >> 1;

    auto issue = [&](int ks, int buf) {
        _Float16* base = &S[buf * BUFSZ];
#pragma unroll
        for (int r = 0; r < 2; ++r) {
            const int i = w * 2 + r;
            const size_t ga = ((size_t)(ks * MC + bm4 + i)) * 512 + lane * 8;
            async16(Xh + ga, base + AH + i * 512);
            async16(Xl + ga, base + AL + i * 512);
        }
        const size_t gb = ((size_t)(ks * NC + bn4 + w)) * 512 + lane * 8;
        async16(Wh + gb, base + BH + w * 512);
        async16(Wl + gb, base + BL + w * 512);
    };

    floatx4 acc0[4][2] = {};
    floatx4 acc1[4][2] = {};

    issue(0, 0);
    for (int it = 0; it < KS; ++it) {
        const int buf = it & 1;
        __syncthreads();
        if (it + 1 < KS) issue(it + 1, buf ^ 1);

        const _Float16* base = &S[buf * BUFSZ];
        half8 ah[4], al[4], bh[2], bl[2];
#pragma unroll
        for (int mt = 0; mt < 4; ++mt) {
            ah[mt] = *(const half8*)(base + AH + (wm * 4 + mt) * 512 + lane * 8);
            al[mt] = *(const half8*)(base + AL + (wm * 4 + mt) * 512 + lane * 8);
        }
#pragma unroll
        for (int nt = 0; nt < 2; ++nt) {
            bh[nt] = *(const half8*)(base + BH + (wn * 2 + nt) * 512 + lane * 8);
            bl[nt] = *(const half8*)(base + BL + (wn * 2 + nt) * 512 + lane * 8);
        }
#pragma unroll
        for (int mt = 0; mt < 4; ++mt)
#pragma unroll
            for (int nt = 0; nt < 2; ++nt) {
                acc0[mt][nt] = __builtin_amdgcn_mfma_f32_16x16x32_f16(ah[mt], bh[nt], acc0[mt][nt], 0, 0, 0);
                acc1[mt][nt] = __builtin_amdgcn_mfma_f32_16x16x32_f16(ah[mt], bl[nt], acc1[mt][nt], 0, 0, 0);
                acc1[mt][nt] = __builtin_amdgcn_mfma_f32_16x16x32_f16(al[mt], bh[nt], acc1[mt][nt], 0, 0, 0);
            }
    }

    const int fr = lane & 15;
    const int fq = lane >> 4;
#pragma unroll
    for (int nt = 0; nt < 2; ++nt) {
        const int n = nb * 64 + wn * 32 + nt * 16 + fr;
        if (n >= Hn) continue;
#pragma unroll
        for (int mt = 0; mt < 4; ++mt) {
            const int m = mb * 128 + wm * 64 + mt * 16 + fq * 4;
#pragma unroll
            for (int r = 0; r < 4; ++r)
                H1[(size_t)(m + r) * Hn + n] =
                    acc0[mt][nt][r] + acc1[mt][nt][r] * (1.0f / 4096.0f);
        }
    }
}

// ---------------------------------------------------------------------------
// GEMM small-ws fallback (r3-verified; bias removed).
// ---------------------------------------------------------------------------
__global__ __launch_bounds__(256, 4)
void gemm_fb(const float* __restrict__ X, const float* __restrict__ W1,
             float* __restrict__ H1)
{
    constexpr int K = Dn;
    constexpr int LD = 72;
    __shared__ __align__(16) _Float16 As[2][64][LD];
    __shared__ __align__(16) _Float16 Bs[2][64][LD];

    const int tid = threadIdx.x;
    const int bm = blockIdx.x * 64;
    const int bn = blockIdx.y * 64;
    const int lane = tid & 63;
    const int wid = tid >> 6;
    const int wm = (wid & 1) * 32;
    const int wn = (wid >> 1) * 32;
    const int fr = lane & 15;
    const int fq = lane >> 4;

    const int row0 = tid >> 3;
    const int row1 = (tid + 256) >> 3;
    const int k8_0 = (tid & 7) * 8;

    float4 rx[2][2], rw[2][2];
    const float zero4[4] = {0.f, 0.f, 0.f, 0.f};

    auto load_tiles = [&](int k0) {
        rx[0][0] = *(const float4*)(X + (size_t)(bm + row0) * K + k0 + k8_0);
        rx[0][1] = *(const float4*)(X + (size_t)(bm + row0) * K + k0 + k8_0 + 4);
        rx[1][0] = *(const float4*)(X + (size_t)(bm + row1) * K + k0 + k8_0);
        rx[1][1] = *(const float4*)(X + (size_t)(bm + row1) * K + k0 + k8_0 + 4);
        const int n0 = bn + row0, n1 = bn + row1;
        if (n0 < Hn) {
            rw[0][0] = *(const float4*)(W1 + (size_t)n0 * K + k0 + k8_0);
            rw[0][1] = *(const float4*)(W1 + (size_t)n0 * K + k0 + k8_0 + 4);
        } else { rw[0][0] = *(const float4*)zero4; rw[0][1] = *(const float4*)zero4; }
        if (n1 < Hn) {
            rw[1][0] = *(const float4*)(W1 + (size_t)n1 * K + k0 + k8_0);
            rw[1][1] = *(const float4*)(W1 + (size_t)n1 * K + k0 + k8_0 + 4);
        } else { rw[1][0] = *(const float4*)zero4; rw[1][1] = *(const float4*)zero4; }
    };

    load_tiles(0);
    floatx4 acc0[2][2] = {};
    floatx4 acc1[2][2] = {};

    for (int k0 = 0; k0 < K; k0 += 64) {
#pragma unroll
        for (int p = 0; p < 2; ++p) {
            const int row = p ? row1 : row0;
            float v[8];
            *(float4*)&v[0] = rx[p][0]; *(float4*)&v[4] = rx[p][1];
            half8 hi, lo;
#pragma unroll
            for (int j = 0; j < 8; ++j) {
                hi[j] = (_Float16)v[j];
                lo[j] = (_Float16)((v[j] - (float)hi[j]) * 4096.0f);
            }
            *(half8*)&As[0][row][k8_0] = hi;
            *(half8*)&As[1][row][k8_0] = lo;

            *(float4*)&v[0] = rw[p][0]; *(float4*)&v[4] = rw[p][1];
#pragma unroll
            for (int j = 0; j < 8; ++j) {
                hi[j] = (_Float16)v[j];
                lo[j] = (_Float16)((v[j] - (float)hi[j]) * 4096.0f);
            }
            *(half8*)&Bs[0][row][k8_0] = hi;
            *(half8*)&Bs[1][row][k8_0] = lo;
        }
        __syncthreads();
        if (k0 + 64 < K) load_tiles(k0 + 64);

#pragma unroll
        for (int c = 0; c < 2; ++c) {
            half8 ahi[2], alo[2], bhi[2], blo[2];
#pragma unroll
            for (int mt = 0; mt < 2; ++mt) {
                ahi[mt] = *(const half8*)&As[0][wm + mt * 16 + fr][c * 32 + fq * 8];
                alo[mt] = *(const half8*)&As[1][wm + mt * 16 + fr][c * 32 + fq * 8];
            }
#pragma unroll
            for (int nt = 0; nt < 2; ++nt) {
                bhi[nt] = *(const half8*)&Bs[0][wn + nt * 16 + fr][c * 32 + fq * 8];
                blo[nt] = *(const half8*)&Bs[1][wn + nt * 16 + fr][c * 32 + fq * 8];
            }
#pragma unroll
            for (int mt = 0; mt < 2; ++mt)
#pragma unroll
                for (int nt = 0; nt < 2; ++nt) {
                    acc0[mt][nt] = __builtin_amdgcn_mfma_f32_16x16x32_f16(ahi[mt], bhi[nt], acc0[mt][nt], 0, 0, 0);
                    acc1[mt][nt] = __builtin_amdgcn_mfma_f32_16x16x32_f16(ahi[mt], blo[nt], acc1[mt][nt], 0, 0, 0);
                    acc1[mt][nt] = __builtin_amdgcn_mfma_f32_16x16x32_f16(alo[mt], bhi[nt], acc1[mt][nt], 0, 0, 0);
                }
        }
        __syncthreads();
    }

#pragma unroll
    for (int nt = 0; nt < 2; ++nt) {
        const int n = bn + wn + nt * 16 + fr;
        if (n >= Hn) continue;
#pragma unroll
        for (int mt = 0; mt < 2; ++mt) {
            const int m = bm + wm + mt * 16 + fq * 4;
#pragma unroll
            for (int r = 0; r < 4; ++r)
                H1[(size_t)(m + r) * Hn + n] =
                    acc0[mt][nt][r] + acc1[mt][nt][r] * (1.0f / 4096.0f);
        }
    }
}

// ---------------------------------------------------------------------------
// LIF scan (r4-r7 verified) + bias add + optional split-K partial sum.
// ---------------------------------------------------------------------------
__global__ __launch_bounds__(1024)
void snn_scan(const float* __restrict__ H1, const float* __restrict__ b1,
              const float* __restrict__ W2, const float* __restrict__ b2,
              float* __restrict__ out, int split)
{
    const int b = blockIdx.x;
    const int tid = threadIdx.x;
    const int lane = tid & 63;
    const int wid = tid >> 6;
    const bool act = (tid < Hn);
    constexpr size_t MH = (size_t)Mn * Hn;

    __shared__ float w2s[1024][5];
    __shared__ unsigned smask[1024];
    __shared__ float h2s[Tn][An];

#pragma unroll
    for (int a = 0; a < An; ++a)
        w2s[tid][a] = act ? W2[a * Hn + tid] : 0.f;

    const float b1v = act ? b1[tid] : 0.f;

    float cur[Tn];
#pragma unroll
    for (int t = 0; t < Tn; ++t) {
        const size_t idx = ((size_t)b * Tn + t) * Hn + tid;
        float c = act ? H1[idx] : 0.f;
        if (split && act) c += H1[idx + MH];
        cur[t] = c + b1v;
    }

    unsigned mask = 0;
    float mem1 = 0.f;
#pragma unroll
    for (int t = 0; t < Tn; ++t) {
        const float reset = (mem1 > 1.0f) ? 1.0f : 0.0f;
        mem1 = (0.99f * mem1 + cur[t]) * (1.0f - reset);
        if (mem1 > 1.0f) mask |= (1u << t);
    }
    smask[tid] = act ? mask : 0u;
    __syncthreads();

#pragma unroll
    for (int tt = 0; tt < 2; ++tt) {
        const int t = wid * 2 + tt;
        float p[An] = {0.f, 0.f, 0.f, 0.f};
        for (int h = lane; h < 1024; h += 64) {
            const float g = (smask[h] >> t) & 1u ? 1.0f : 0.0f;
#pragma unroll
            for (int a = 0; a < An; ++a) p[a] += g * w2s[h][a];
        }
#pragma unroll
        for (int off = 32; off > 0; off >>= 1)
#pragma unroll
            for (int a = 0; a < An; ++a) p[a] += __shfl_down(p[a], off, 64);
        if (lane == 0) {
#pragma unroll
            for (int a = 0; a < An; ++a) h2s[t][a] = p[a];
        }
    }
    __syncthreads();

    if (tid < An) {
        const float bias = b2[tid];
        float mem2 = 0.f;
#pragma unroll
        for (int t = 0; t < Tn; ++t) {
            const float h2 = h2s[t][tid] + bias;
            const float reset = (mem2 > 1.0f) ? 1.0f : 0.0f;
            mem2 = (0.99f * mem2 + h2) * (1.0f - reset);
            out[((size_t)b * Tn + t) * An + tid] = (mem2 > 1.0f) ? 1.0f : 0.0f;
        }
    }
}

extern "C" void kernel_launch(void* const* d_in, const int* in_sizes, int n_in,
                              void* d_out, int out_size, void* d_ws, size_t ws_size,
                              hipStream_t stream) {
    const float* x  = (const float*)d_in[0];   // [B,T,D]
    const float* W1 = (const float*)d_in[1];   // [H,D]
    const float* b1 = (const float*)d_in[2];   // [H]
    const float* W2 = (const float*)d_in[3];   // [A,H]
    const float* b2 = (const float*)d_in[4];   // [A]
    float* out = (float*)d_out;                // [B,T,A]

    char* ws = (char*)d_ws;
    float* H1 = (float*)ws;

    if (ws_size >= WS_SPLITK) {
        _Float16* Xh = (_Float16*)(ws + 2 * H1_BYTES);
        _Float16* Xl = (_Float16*)(ws + 2 * H1_BYTES + XS_BYTES);
        _Float16* Wh = (_Float16*)(ws + 2 * H1_BYTES + 2 * XS_BYTES);
        _Float16* Wl = (_Float16*)(ws + 2 * H1_BYTES + 2 * XS_BYTES + WSp_BYTES);

        cvt2<<<256 * 25 + 64 * 25, 256, 0, stream>>>(x, W1, Xh, Xl, Wh, Wl);
        gemm_sk<<<512, 256, 0, stream>>>(Xh, Xl, Wh, Wl, H1);   // kh=&1, nb=(>>1)&7, mb=>>4
        snn_scan<<<Bn, 1024, 0, stream>>>(H1, b1, W2, b2, out, 1);
    } else if (ws_size >= WS_R7) {
        _Float16* Xh = (_Float16*)(ws + H1_BYTES);
        _Float16* Xl = (_Float16*)(ws + H1_BYTES + XS_BYTES);
        _Float16* Wh = (_Float16*)(ws + H1_BYTES + 2 * XS_BYTES);
        _Float16* Wl = (_Float16*)(ws + H1_BYTES + 2 * XS_BYTES + WSp_BYTES);

        cvt2<<<256 * 25 + 64 * 25, 256, 0, stream>>>(x, W1, Xh, Xl, Wh, Wl);
        gemm_frag2<<<512, 256, 0, stream>>>(Xh, Xl, Wh, Wl, H1);
        snn_scan<<<Bn, 1024, 0, stream>>>(H1, b1, W2, b2, out, 0);
    } else {
        dim3 grid(Mn / 64, (Hn + 63) / 64);
        gemm_fb<<<grid, 256, 0, stream>>>(x, W1, H1);
        snn_scan<<<Bn, 1024, 0, stream>>>(H1, b1, W2, b2, out, 0);
    }
}

// Round 9
// 346.074 us; speedup vs baseline: 2.1283x; 1.0100x over previous
//
#include <hip/hip_runtime.h>
#include <hip/hip_bf16.h>

// Problem constants (fixed by reference setup_inputs)
constexpr int Bn = 128;   // batch
constexpr int Tn = 32;    // timesteps
constexpr int Dn = 6400;  // input dim (K)
constexpr int Hn = 1000;  // hidden  (N)
constexpr int An = 4;     // actions
constexpr int Mn = Bn * Tn;   // 4096 GEMM rows
constexpr int Npad = 1024;    // W rows padded -> no N-guards in GEMM

constexpr int KS = Dn / 32;   // 200 k-chunks of 32
constexpr int MC = Mn / 16;   // 256 m-chunks of 16 rows
constexpr int NC = Npad / 16; // 64  n-chunks of 16 rows

typedef _Float16 half8 __attribute__((ext_vector_type(8)));
typedef _Float16 half4 __attribute__((ext_vector_type(4)));
typedef float floatx4 __attribute__((ext_vector_type(4)));

// Workspace layouts (bytes)
constexpr size_t H1_BYTES  = (size_t)Mn * Hn * 4;       // 16,384,000
constexpr size_t XS_BYTES  = (size_t)Mn * Dn * 2;       // per split
constexpr size_t WSp_BYTES = (size_t)Npad * Dn * 2;     // per split
constexpr size_t WS_R7     = H1_BYTES + 2 * XS_BYTES + 2 * WSp_BYTES;      // 147,456,000
constexpr size_t WS_SPLITK = 2 * H1_BYTES + 2 * XS_BYTES + 2 * WSp_BYTES;  // 163,840,000

__device__ __forceinline__ void async16(const void* g, void* l) {
    __builtin_amdgcn_global_load_lds(
        (const __attribute__((address_space(1))) void*)g,
        (__attribute__((address_space(3))) void*)l, 16, 0, 0);
}

// ---------------------------------------------------------------------------
// Pre-pass (r7/r8-verified): fp16 hi/lo split into fragment-chunk layout,
// both sides 1KB-per-instruction coalesced via LDS transpose.
// ---------------------------------------------------------------------------
__global__ __launch_bounds__(256)
void cvt2(const float* __restrict__ X, const float* __restrict__ W1,
          _Float16* __restrict__ Xh, _Float16* __restrict__ Xl,
          _Float16* __restrict__ Wh, _Float16* __restrict__ Wl)
{
    constexpr int LD2 = 264;
    __shared__ __align__(16) _Float16 hiS[16][LD2];
    __shared__ __align__(16) _Float16 loS[16][LD2];

    const int tid = threadIdx.x;
    const int lane = tid & 63;
    const int w = tid >> 6;
    const int bx = blockIdx.x;

    const float* src;
    _Float16 *dh, *dl;
    int c4, ks0, crow, nrows;
    if (bx < 256 * 25) {                       // X part
        c4 = bx & 255; ks0 = (bx >> 8) * 8;
        src = X; dh = Xh; dl = Xl; crow = MC; nrows = 16;
    } else {                                   // W part (rows >= Hn zeroed)
        const int b2 = bx - 256 * 25;
        c4 = b2 & 63; ks0 = (b2 >> 6) * 8;
        src = W1; dh = Wh; dl = Wl; crow = NC; nrows = Hn - c4 * 16;
    }

#pragma unroll
    for (int j = 0; j < 4; ++j) {
        const int row = w * 4 + j;
        float4 v = make_float4(0.f, 0.f, 0.f, 0.f);
        if (row < nrows)
            v = *(const float4*)(src + (size_t)(c4 * 16 + row) * Dn + ks0 * 32 + lane * 4);
        half4 hi, lo;
        hi[0] = (_Float16)v.x; lo[0] = (_Float16)((v.x - (float)hi[0]) * 4096.0f);
        hi[1] = (_Float16)v.y; lo[1] = (_Float16)((v.y - (float)hi[1]) * 4096.0f);
        hi[2] = (_Float16)v.z; lo[2] = (_Float16)((v.z - (float)hi[2]) * 4096.0f);
        hi[3] = (_Float16)v.w; lo[3] = (_Float16)((v.w - (float)hi[3]) * 4096.0f);
        *(half4*)&hiS[row][lane * 4] = hi;
        *(half4*)&loS[row][lane * 4] = lo;
    }
    __syncthreads();

    const int lr = lane & 15, lg = lane >> 4;
#pragma unroll
    for (int q = 0; q < 2; ++q) {
        const int ks = w * 2 + q;
        const size_t cbase = ((size_t)(ks0 + ks) * crow + c4) * 512;
        const half8 h = *(const half8*)&hiS[lr][ks * 32 + lg * 8];
        const half8 l = *(const half8*)&loS[lr][ks * 32 + lg * 8];
        *(half8*)(dh + cbase + lane * 8) = h;
        *(half8*)(dl + cbase + lane * 8) = l;
    }
}

// ---------------------------------------------------------------------------
// GEMM (primary): 128x128 tile, split-K=2, A via LDS / B direct-to-register.
// r8 was LDS-BW-bound (96 KB LDS traffic/block-iter = 1130 cyc vs 931 cyc
// MFMA). With the fragment-chunk layout, B fragment loads are lane-contiguous
// 1 KB global_load_dwordx4 -> read B straight to VGPRs (L1 absorbs the
// wave-pair's x2 reuse). LDS now carries only A: 16 KB stage + 32 KB reads
// = 48 KB/block-iter (~565 cyc) -- comfortably under MFMA. Single-buffer B
// regs keep VGPR+acc <= ~230 so 2 blocks/CU stay co-resident (dbuf A = 32 KB
// LDS/block). One barrier/iter guards only the A double-buffer.
// ---------------------------------------------------------------------------
__global__ __launch_bounds__(256, 2)
void gemm_sk2(const _Float16* __restrict__ Xh, const _Float16* __restrict__ Xl,
              const _Float16* __restrict__ Wh, const _Float16* __restrict__ Wl,
              float* __restrict__ H1)
{
    __shared__ __align__(16) _Float16 S[2][16][512];   // 32 KB: [buf][A chunk hi0-7,lo0-7][1KB]

    const int tid = threadIdx.x;
    const int lane = tid & 63;
    const int w = tid >> 6;
    const int kh = blockIdx.x & 1;
    const int nb = (blockIdx.x >> 1) & 7;
    const int mb = blockIdx.x >> 4;
    const int bm8 = mb * 8;
    const int bn8 = nb * 8;
    const int wm = w & 1;
    const int wn = w >> 1;
    const int ks0 = kh * (KS / 2);

    // A staging: wave w stages hi+lo of m-chunks 2w, 2w+1 (4 async16/wave).
    auto issueA = [&](int ks, int buf) {
        _Float16* base = &S[buf][0][0];
#pragma unroll
        for (int r = 0; r < 2; ++r) {
            const int i = w * 2 + r;
            const size_t ga = ((size_t)(ks * MC + bm8 + i)) * 512 + lane * 8;
            async16(Xh + ga, base + (0 + i) * 512);
            async16(Xl + ga, base + (8 + i) * 512);
        }
    };

    // B fragments: direct global->VGPR, lane-contiguous 1 KB per instruction.
    const _Float16* bhp = Wh + ((size_t)(ks0 * NC + bn8 + wn * 4)) * 512 + lane * 8;
    const _Float16* blp = Wl + ((size_t)(ks0 * NC + bn8 + wn * 4)) * 512 + lane * 8;
    constexpr size_t BSTEP = (size_t)NC * 512;         // per-ks advance (halves)

    floatx4 acc0[4][4] = {};
    floatx4 acc1[4][4] = {};

    issueA(ks0, 0);
    for (int it = 0; it < KS / 2; ++it) {
        const int buf = it & 1;
        __syncthreads();                   // A DMA for buf landed; buf^1 free
        if (it + 1 < KS / 2) issueA(ks0 + it + 1, buf ^ 1);

        // B loads for THIS iter (latency overlapped by the A ds_read burst)
        half8 bh[4], bl[4];
        const size_t bo = (size_t)it * BSTEP;
#pragma unroll
        for (int nt = 0; nt < 4; ++nt) {
            bh[nt] = *(const half8*)(bhp + bo + nt * 512);
            bl[nt] = *(const half8*)(blp + bo + nt * 512);
        }

        half8 ah[4], al[4];
#pragma unroll
        for (int mt = 0; mt < 4; ++mt) {
            ah[mt] = *(const half8*)&S[buf][wm * 4 + mt][lane * 8];
            al[mt] = *(const half8*)&S[buf][8 + wm * 4 + mt][lane * 8];
        }

#pragma unroll
        for (int mt = 0; mt < 4; ++mt)
#pragma unroll
            for (int nt = 0; nt < 4; ++nt) {
                acc0[mt][nt] = __builtin_amdgcn_mfma_f32_16x16x32_f16(ah[mt], bh[nt], acc0[mt][nt], 0, 0, 0);
                acc1[mt][nt] = __builtin_amdgcn_mfma_f32_16x16x32_f16(ah[mt], bl[nt], acc1[mt][nt], 0, 0, 0);
                acc1[mt][nt] = __builtin_amdgcn_mfma_f32_16x16x32_f16(al[mt], bh[nt], acc1[mt][nt], 0, 0, 0);
            }
    }

    // epilogue (no bias -- scan adds b1): C/D col=lane&15, row=(lane>>4)*4+r
    float* H1o = H1 + (size_t)kh * ((size_t)Mn * Hn);
    const int fr = lane & 15;
    const int fq = lane >> 4;
#pragma unroll
    for (int nt = 0; nt < 4; ++nt) {
        const int n = nb * 128 + wn * 64 + nt * 16 + fr;
        if (n >= Hn) continue;
#pragma unroll
        for (int mt = 0; mt < 4; ++mt) {
            const int m = mb * 128 + wm * 64 + mt * 16 + fq * 4;
#pragma unroll
            for (int r = 0; r < 4; ++r)
                H1o[(size_t)(m + r) * Hn + n] =
                    acc0[mt][nt][r] + acc1[mt][nt][r] * (1.0f / 4096.0f);
        }
    }
}

// ---------------------------------------------------------------------------
// GEMM mid-fallback (r7-verified; bias removed): ws in [147,164) MB.
// ---------------------------------------------------------------------------
constexpr int AH = 0;
constexpr int AL = 8 * 512;
constexpr int BH = 16 * 512;
constexpr int BL = 20 * 512;
constexpr int BUFSZ = 24 * 512;

__global__ __launch_bounds__(256, 2)
void gemm_frag2(const _Float16* __restrict__ Xh, const _Float16* __restrict__ Xl,
                const _Float16* __restrict__ Wh, const _Float16* __restrict__ Wl,
                float* __restrict__ H1)
{
    __shared__ __align__(16) _Float16 S[2 * BUFSZ];

    const int tid = threadIdx.x;
    const int lane = tid & 63;
    const int w = tid >> 6;
    const int nb = blockIdx.x & 15;
    const int mb = blockIdx.x >> 4;
    const int bm4 = mb * 8;
    const int bn4 = nb * 4;
    const int wm = w & 1;
    const int wn = w >> 1;

    auto issue = [&](int ks, int buf) {
        _Float16* base = &S[buf * BUFSZ];
#pragma unroll
        for (int r = 0; r < 2; ++r) {
            const int i = w * 2 + r;
            const size_t ga = ((size_t)(ks * MC + bm4 + i)) * 512 + lane * 8;
            async16(Xh + ga, base + AH + i * 512);
            async16(Xl + ga, base + AL + i * 512);
        }
        const size_t gb = ((size_t)(ks * NC + bn4 + w)) * 512 + lane * 8;
        async16(Wh + gb, base + BH + w * 512);
        async16(Wl + gb, base + BL + w * 512);
    };

    floatx4 acc0[4][2] = {};
    floatx4 acc1[4][2] = {};

    issue(0, 0);
    for (int it = 0; it < KS; ++it) {
        const int buf = it & 1;
        __syncthreads();
        if (it + 1 < KS) issue(it + 1, buf ^ 1);

        const _Float16* base = &S[buf * BUFSZ];
        half8 ah[4], al[4], bh[2], bl[2];
#pragma unroll
        for (int mt = 0; mt < 4; ++mt) {
            ah[mt] = *(const half8*)(base + AH + (wm * 4 + mt) * 512 + lane * 8);
            al[mt] = *(const half8*)(base + AL + (wm * 4 + mt) * 512 + lane * 8);
        }
#pragma unroll
        for (int nt = 0; nt < 2; ++nt) {
            bh[nt] = *(const half8*)(base + BH + (wn * 2 + nt) * 512 + lane * 8);
            bl[nt] = *(const half8*)(base + BL + (wn * 2 + nt) * 512 + lane * 8);
        }
#pragma unroll
        for (int mt = 0; mt < 4; ++mt)
#pragma unroll
            for (int nt = 0; nt < 2; ++nt) {
                acc0[mt][nt] = __builtin_amdgcn_mfma_f32_16x16x32_f16(ah[mt], bh[nt], acc0[mt][nt], 0, 0, 0);
                acc1[mt][nt] = __builtin_amdgcn_mfma_f32_16x16x32_f16(ah[mt], bl[nt], acc1[mt][nt], 0, 0, 0);
                acc1[mt][nt] = __builtin_amdgcn_mfma_f32_16x16x32_f16(al[mt], bh[nt], acc1[mt][nt], 0, 0, 0);
            }
    }

    const int fr = lane & 15;
    const int fq = lane >> 4;
#pragma unroll
    for (int nt = 0; nt < 2; ++nt) {
        const int n = nb * 64 + wn * 32 + nt * 16 + fr;
        if (n >= Hn) continue;
#pragma unroll
        for (int mt = 0; mt < 4; ++mt) {
            const int m = mb * 128 + wm * 64 + mt * 16 + fq * 4;
#pragma unroll
            for (int r = 0; r < 4; ++r)
                H1[(size_t)(m + r) * Hn + n] =
                    acc0[mt][nt][r] + acc1[mt][nt][r] * (1.0f / 4096.0f);
        }
    }
}

// ---------------------------------------------------------------------------
// GEMM small-ws fallback (r3-verified; bias removed).
// ---------------------------------------------------------------------------
__global__ __launch_bounds__(256, 4)
void gemm_fb(const float* __restrict__ X, const float* __restrict__ W1,
             float* __restrict__ H1)
{
    constexpr int K = Dn;
    constexpr int LD = 72;
    __shared__ __align__(16) _Float16 As[2][64][LD];
    __shared__ __align__(16) _Float16 Bs[2][64][LD];

    const int tid = threadIdx.x;
    const int bm = blockIdx.x * 64;
    const int bn = blockIdx.y * 64;
    const int lane = tid & 63;
    const int wid = tid >> 6;
    const int wm = (wid & 1) * 32;
    const int wn = (wid >> 1) * 32;
    const int fr = lane & 15;
    const int fq = lane >> 4;

    const int row0 = tid >> 3;
    const int row1 = (tid + 256) >> 3;
    const int k8_0 = (tid & 7) * 8;

    float4 rx[2][2], rw[2][2];
    const float zero4[4] = {0.f, 0.f, 0.f, 0.f};

    auto load_tiles = [&](int k0) {
        rx[0][0] = *(const float4*)(X + (size_t)(bm + row0) * K + k0 + k8_0);
        rx[0][1] = *(const float4*)(X + (size_t)(bm + row0) * K + k0 + k8_0 + 4);
        rx[1][0] = *(const float4*)(X + (size_t)(bm + row1) * K + k0 + k8_0);
        rx[1][1] = *(const float4*)(X + (size_t)(bm + row1) * K + k0 + k8_0 + 4);
        const int n0 = bn + row0, n1 = bn + row1;
        if (n0 < Hn) {
            rw[0][0] = *(const float4*)(W1 + (size_t)n0 * K + k0 + k8_0);
            rw[0][1] = *(const float4*)(W1 + (size_t)n0 * K + k0 + k8_0 + 4);
        } else { rw[0][0] = *(const float4*)zero4; rw[0][1] = *(const float4*)zero4; }
        if (n1 < Hn) {
            rw[1][0] = *(const float4*)(W1 + (size_t)n1 * K + k0 + k8_0);
            rw[1][1] = *(const float4*)(W1 + (size_t)n1 * K + k0 + k8_0 + 4);
        } else { rw[1][0] = *(const float4*)zero4; rw[1][1] = *(const float4*)zero4; }
    };

    load_tiles(0);
    floatx4 acc0[2][2] = {};
    floatx4 acc1[2][2] = {};

    for (int k0 = 0; k0 < K; k0 += 64) {
#pragma unroll
        for (int p = 0; p < 2; ++p) {
            const int row = p ? row1 : row0;
            float v[8];
            *(float4*)&v[0] = rx[p][0]; *(float4*)&v[4] = rx[p][1];
            half8 hi, lo;
#pragma unroll
            for (int j = 0; j < 8; ++j) {
                hi[j] = (_Float16)v[j];
                lo[j] = (_Float16)((v[j] - (float)hi[j]) * 4096.0f);
            }
            *(half8*)&As[0][row][k8_0] = hi;
            *(half8*)&As[1][row][k8_0] = lo;

            *(float4*)&v[0] = rw[p][0]; *(float4*)&v[4] = rw[p][1];
#pragma unroll
            for (int j = 0; j < 8; ++j) {
                hi[j] = (_Float16)v[j];
                lo[j] = (_Float16)((v[j] - (float)hi[j]) * 4096.0f);
            }
            *(half8*)&Bs[0][row][k8_0] = hi;
            *(half8*)&Bs[1][row][k8_0] = lo;
        }
        __syncthreads();
        if (k0 + 64 < K) load_tiles(k0 + 64);

#pragma unroll
        for (int c = 0; c < 2; ++c) {
            half8 ahi[2], alo[2], bhi[2], blo[2];
#pragma unroll
            for (int mt = 0; mt < 2; ++mt) {
                ahi[mt] = *(const half8*)&As[0][wm + mt * 16 + fr][c * 32 + fq * 8];
                alo[mt] = *(const half8*)&As[1][wm + mt * 16 + fr][c * 32 + fq * 8];
            }
#pragma unroll
            for (int nt = 0; nt < 2; ++nt) {
                bhi[nt] = *(const half8*)&Bs[0][wn + nt * 16 + fr][c * 32 + fq * 8];
                blo[nt] = *(const half8*)&Bs[1][wn + nt * 16 + fr][c * 32 + fq * 8];
            }
#pragma unroll
            for (int mt = 0; mt < 2; ++mt)
#pragma unroll
                for (int nt = 0; nt < 2; ++nt) {
                    acc0[mt][nt] = __builtin_amdgcn_mfma_f32_16x16x32_f16(ahi[mt], bhi[nt], acc0[mt][nt], 0, 0, 0);
                    acc1[mt][nt] = __builtin_amdgcn_mfma_f32_16x16x32_f16(ahi[mt], blo[nt], acc1[mt][nt], 0, 0, 0);
                    acc1[mt][nt] = __builtin_amdgcn_mfma_f32_16x16x32_f16(alo[mt], bhi[nt], acc1[mt][nt], 0, 0, 0);
                }
        }
        __syncthreads();
    }

#pragma unroll
    for (int nt = 0; nt < 2; ++nt) {
        const int n = bn + wn + nt * 16 + fr;
        if (n >= Hn) continue;
#pragma unroll
        for (int mt = 0; mt < 2; ++mt) {
            const int m = bm + wm + mt * 16 + fq * 4;
#pragma unroll
            for (int r = 0; r < 4; ++r)
                H1[(size_t)(m + r) * Hn + n] =
                    acc0[mt][nt][r] + acc1[mt][nt][r] * (1.0f / 4096.0f);
        }
    }
}

// ---------------------------------------------------------------------------
// LIF scan (r4-r8 verified) + bias add + optional split-K partial sum.
// ---------------------------------------------------------------------------
__global__ __launch_bounds__(1024)
void snn_scan(const float* __restrict__ H1, const float* __restrict__ b1,
              const float* __restrict__ W2, const float* __restrict__ b2,
              float* __restrict__ out, int split)
{
    const int b = blockIdx.x;
    const int tid = threadIdx.x;
    const int lane = tid & 63;
    const int wid = tid >> 6;
    const bool act = (tid < Hn);
    constexpr size_t MH = (size_t)Mn * Hn;

    __shared__ float w2s[1024][5];
    __shared__ unsigned smask[1024];
    __shared__ float h2s[Tn][An];

#pragma unroll
    for (int a = 0; a < An; ++a)
        w2s[tid][a] = act ? W2[a * Hn + tid] : 0.f;

    const float b1v = act ? b1[tid] : 0.f;

    float cur[Tn];
#pragma unroll
    for (int t = 0; t < Tn; ++t) {
        const size_t idx = ((size_t)b * Tn + t) * Hn + tid;
        float c = act ? H1[idx] : 0.f;
        if (split && act) c += H1[idx + MH];
        cur[t] = c + b1v;
    }

    unsigned mask = 0;
    float mem1 = 0.f;
#pragma unroll
    for (int t = 0; t < Tn; ++t) {
        const float reset = (mem1 > 1.0f) ? 1.0f : 0.0f;
        mem1 = (0.99f * mem1 + cur[t]) * (1.0f - reset);
        if (mem1 > 1.0f) mask |= (1u << t);
    }
    smask[tid] = act ? mask : 0u;
    __syncthreads();

#pragma unroll
    for (int tt = 0; tt < 2; ++tt) {
        const int t = wid * 2 + tt;
        float p[An] = {0.f, 0.f, 0.f, 0.f};
        for (int h = lane; h < 1024; h += 64) {
            const float g = (smask[h] >> t) & 1u ? 1.0f : 0.0f;
#pragma unroll
            for (int a = 0; a < An; ++a) p[a] += g * w2s[h][a];
        }
#pragma unroll
        for (int off = 32; off > 0; off >>= 1)
#pragma unroll
            for (int a = 0; a < An; ++a) p[a] += __shfl_down(p[a], off, 64);
        if (lane == 0) {
#pragma unroll
            for (int a = 0; a < An; ++a) h2s[t][a] = p[a];
        }
    }
    __syncthreads();

    if (tid < An) {
        const float bias = b2[tid];
        float mem2 = 0.f;
#pragma unroll
        for (int t = 0; t < Tn; ++t) {
            const float h2 = h2s[t][tid] + bias;
            const float reset = (mem2 > 1.0f) ? 1.0f : 0.0f;
            mem2 = (0.99f * mem2 + h2) * (1.0f - reset);
            out[((size_t)b * Tn + t) * An + tid] = (mem2 > 1.0f) ? 1.0f : 0.0f;
        }
    }
}

extern "C" void kernel_launch(void* const* d_in, const int* in_sizes, int n_in,
                              void* d_out, int out_size, void* d_ws, size_t ws_size,
                              hipStream_t stream) {
    const float* x  = (const float*)d_in[0];   // [B,T,D]
    const float* W1 = (const float*)d_in[1];   // [H,D]
    const float* b1 = (const float*)d_in[2];   // [H]
    const float* W2 = (const float*)d_in[3];   // [A,H]
    const float* b2 = (const float*)d_in[4];   // [A]
    float* out = (float*)d_out;                // [B,T,A]

    char* ws = (char*)d_ws;
    float* H1 = (float*)ws;

    if (ws_size >= WS_SPLITK) {
        _Float16* Xh = (_Float16*)(ws + 2 * H1_BYTES);
        _Float16* Xl = (_Float16*)(ws + 2 * H1_BYTES + XS_BYTES);
        _Float16* Wh = (_Float16*)(ws + 2 * H1_BYTES + 2 * XS_BYTES);
        _Float16* Wl = (_Float16*)(ws + 2 * H1_BYTES + 2 * XS_BYTES + WSp_BYTES);

        cvt2<<<256 * 25 + 64 * 25, 256, 0, stream>>>(x, W1, Xh, Xl, Wh, Wl);
        gemm_sk2<<<512, 256, 0, stream>>>(Xh, Xl, Wh, Wl, H1);   // kh=&1, nb=(>>1)&7, mb=>>4
        snn_scan<<<Bn, 1024, 0, stream>>>(H1, b1, W2, b2, out, 1);
    } else if (ws_size >= WS_R7) {
        _Float16* Xh = (_Float16*)(ws + H1_BYTES);
        _Float16* Xl = (_Float16*)(ws + H1_BYTES + XS_BYTES);
        _Float16* Wh = (_Float16*)(ws + H1_BYTES + 2 * XS_BYTES);
        _Float16* Wl = (_Float16*)(ws + H1_BYTES + 2 * XS_BYTES + WSp_BYTES);

        cvt2<<<256 * 25 + 64 * 25, 256, 0, stream>>>(x, W1, Xh, Xl, Wh, Wl);
        gemm_frag2<<<512, 256, 0, stream>>>(Xh, Xl, Wh, Wl, H1);
        snn_scan<<<Bn, 1024, 0, stream>>>(H1, b1, W2, b2, out, 0);
    } else {
        dim3 grid(Mn / 64, (Hn + 63) / 64);
        gemm_fb<<<grid, 256, 0, stream>>>(x, W1, H1);
        snn_scan<<<Bn, 1024, 0, stream>>>(H1, b1, W2, b2, out, 0);
    }
}